// Round 1
// 200.242 us; speedup vs baseline: 1.0710x; 1.0710x over previous
//
#include <hip/hip_runtime.h>
#include <hip/hip_bf16.h>

typedef unsigned short u16;
typedef short bf16x8 __attribute__((ext_vector_type(8)));
typedef float f32x4 __attribute__((ext_vector_type(4)));

#define S_LEN 2048
#define DQ 512
#define NBATCH 4

__device__ __forceinline__ u16 f2bf(float f) {
    __hip_bfloat16 h = __float2bfloat16(f);
    return *reinterpret_cast<u16*>(&h);
}
__device__ __forceinline__ float bf2f(u16 u) {
    unsigned v = ((unsigned)u) << 16;
    union { unsigned u; float f; } c; c.u = v; return c.f;
}

__device__ __forceinline__ void async16(const u16* g, u16* l) {
    __builtin_amdgcn_global_load_lds(
        (__attribute__((address_space(1))) void*)g,
        (__attribute__((address_space(3))) void*)l, 16, 0, 0);
}

// XCD-chunked bijective swizzle (T1): hardware assigns dispatch id d -> XCD d%8.
// Map d -> logical id so each XCD owns a CONTIGUOUS logical chunk; logical
// neighbors (which share A panels) then share one XCD's private L2.
// Requires nwg % 8 == 0 (all three GEMM grids satisfy this).
__device__ __forceinline__ int xcd_swz(int bid, int chunk) {
    return (bid & 7) * chunk + (bid >> 3);
}

// -------- fp32 -> bf16 convert: x + Wq + Wk + Wv in one launch --------
__global__ __launch_bounds__(256) void k_cvt_all(const float* __restrict__ x,
                                                 const float* __restrict__ wq,
                                                 const float* __restrict__ wk,
                                                 const float* __restrict__ wv,
                                                 u16* __restrict__ xb, u16* __restrict__ wb) {
    int bid = blockIdx.x;
    const float* src;
    u16* dst;
    int i;
    if (bid < 4096)      { src = x;  dst = xb;          i = bid * 256 + threadIdx.x; }
    else if (bid < 4352) { src = wq; dst = wb;          i = (bid - 4096) * 256 + threadIdx.x; }
    else if (bid < 4608) { src = wk; dst = wb + 262144; i = (bid - 4352) * 256 + threadIdx.x; }
    else                 { src = wv; dst = wb + 524288; i = (bid - 4608) * 256 + threadIdx.x; }
    f32x4 v = *(const f32x4*)(src + (size_t)i * 4);
    ushort4 o;
    o.x = f2bf(v.x); o.y = f2bf(v.y); o.z = f2bf(v.z); o.w = f2bf(v.w);
    *(ushort4*)(dst + (size_t)i * 4) = o;
}

// -------- shared 128x128 GEMM core (BK=32): C += A[128 x K] * B[128 x K]^T --------
__device__ __forceinline__ void gemm_core(const u16* __restrict__ A, const u16* __restrict__ B,
                                          int lda, int ldb, int kend,
                                          f32x4 acc[4][4], u16* ldsA, u16* ldsB, int tid) {
    const int lane = tid & 63;
    const int w    = tid >> 6;
    const int wm   = (w & 1) << 6;
    const int wn   = (w >> 1) << 6;
    const int l16  = lane & 15;
    const int quad = lane >> 4;

    for (int k0 = 0; k0 < kend; k0 += 32) {
#pragma unroll
        for (int i = 0; i < 2; ++i) {
            int c  = i * 256 + tid;        // chunk 0..511, 16B each
            int r  = c >> 2;               // row 0..127
            int cc = (c & 3) << 3;         // col element 0/8/16/24
            async16(A + (size_t)r * lda + k0 + cc, ldsA + r * 32 + cc);
            async16(B + (size_t)r * ldb + k0 + cc, ldsB + r * 32 + cc);
        }
        __syncthreads();
        bf16x8 af[4], bf[4];
#pragma unroll
        for (int i = 0; i < 4; ++i)
            af[i] = *(const bf16x8*)(ldsA + (wm + i * 16 + l16) * 32 + quad * 8);
#pragma unroll
        for (int j = 0; j < 4; ++j)
            bf[j] = *(const bf16x8*)(ldsB + (wn + j * 16 + l16) * 32 + quad * 8);
#pragma unroll
        for (int i = 0; i < 4; ++i)
#pragma unroll
            for (int j = 0; j < 4; ++j)
                acc[i][j] = __builtin_amdgcn_mfma_f32_16x16x32_bf16(af[i], bf[j], acc[i][j], 0, 0, 0);
        __syncthreads();
    }
}

// -------- projection: z in {Q,K,V}; Q,K -> row-major bf16; V -> transposed into VT --------
// 1D grid, nwg = 768 = (z=3) x (y=64) x (x=4); chunk = 96 per XCD.
__global__ __launch_bounds__(256) void k_proj(const u16* __restrict__ xb, const u16* __restrict__ Wb,
                                              const float* __restrict__ bq, const float* __restrict__ bk,
                                              const float* __restrict__ bv, u16* __restrict__ out,
                                              u16* __restrict__ VT) {
    __shared__ __align__(16) u16 lds[8192];
    const int l  = xcd_swz(blockIdx.x, 96);
    const int bx = l & 3;
    const int by = (l >> 2) & 63;
    const int z  = l >> 8;
    const int m0 = by * 128, n0 = bx * 128;
    const u16* A = xb + (size_t)m0 * DQ;
    const u16* B = Wb + (size_t)z * DQ * DQ + (size_t)n0 * DQ;
    const float* bias = (z == 0) ? bq : (z == 1) ? bk : bv;

    f32x4 acc[4][4];
#pragma unroll
    for (int i = 0; i < 4; ++i)
#pragma unroll
        for (int j = 0; j < 4; ++j) acc[i][j] = (f32x4)0.0f;

    int tid = threadIdx.x;
    gemm_core(A, B, DQ, DQ, DQ, acc, lds, lds + 4096, tid);

    const int lane = tid & 63, w = tid >> 6;
    const int wm = (w & 1) << 6, wn = (w >> 1) << 6;
    const int l16 = lane & 15, quad = lane >> 4;

    if (z < 2) {
        u16* outz = out + (size_t)z * 8192 * DQ;
#pragma unroll
        for (int j = 0; j < 4; ++j) {
            int gn = n0 + wn + j * 16 + l16;
            float bb = bias[gn];
#pragma unroll
            for (int i = 0; i < 4; ++i)
#pragma unroll
                for (int r = 0; r < 4; ++r) {
                    int gm = m0 + wm + i * 16 + quad * 4 + r;
                    outz[(size_t)gm * DQ + gn] = f2bf(acc[i][j][r] + bb);
                }
        }
    } else {
        // V: write transposed. token gm -> (b = gm>>11, t = gm&2047); feature gn -> VT row.
        const int b = m0 >> 11;                 // m-tile never crosses batch (128 | 2048)
        u16* VTb_ = VT + (size_t)b * DQ * S_LEN;
#pragma unroll
        for (int j = 0; j < 4; ++j) {
            int gn = n0 + wn + j * 16 + l16;
            float bb = bias[gn];
#pragma unroll
            for (int i = 0; i < 4; ++i) {
                int t0 = (m0 & 2047) + wm + i * 16 + quad * 4;
                ushort4 o;
                o.x = f2bf(acc[i][j][0] + bb);
                o.y = f2bf(acc[i][j][1] + bb);
                o.z = f2bf(acc[i][j][2] + bb);
                o.w = f2bf(acc[i][j][3] + bb);
                *(ushort4*)(VTb_ + (size_t)gn * S_LEN + t0) = o;
            }
        }
    }
}

// -------- scores: e = exp(QK^T * scale) -> bf16 into Pb ONLY (no fp32 write) --------
// Scores are bounded (|s| <~ 2.5 after 1/sqrt(512) scaling) -> exp safe without max pass.
// 1D grid, nwg = 1024 = (z=4) x (y=16) x (x=16); chunk = 128 per XCD
// -> per-XCD working set: 8 Q-tiles (1 MB) + K slab (2 MB) = 3 MB, L2-resident.
__global__ __launch_bounds__(256) void k_scores(const u16* __restrict__ Qb, const u16* __restrict__ Kb,
                                                u16* __restrict__ Pb) {
    __shared__ __align__(16) u16 lds[8192];
    const int l  = xcd_swz(blockIdx.x, 128);
    const int bx = l & 15;
    const int by = (l >> 4) & 15;
    const int b  = l >> 8;
    const int m0 = by * 128, n0 = bx * 128;
    const u16* A = Qb + ((size_t)b * S_LEN + m0) * DQ;
    const u16* B = Kb + ((size_t)b * S_LEN + n0) * DQ;

    f32x4 acc[4][4];
#pragma unroll
    for (int i = 0; i < 4; ++i)
#pragma unroll
        for (int j = 0; j < 4; ++j) acc[i][j] = (f32x4)0.0f;

    int tid = threadIdx.x;
    gemm_core(A, B, DQ, DQ, DQ, acc, lds, lds + 4096, tid);

    const float scale = 0.044194173824159216f; // 1/sqrt(512)
    const int lane = tid & 63, w = tid >> 6;
    const int wm = (w & 1) << 6, wn = (w >> 1) << 6;
    const int l16 = lane & 15, quad = lane >> 4;
    u16* prow = Pb + (size_t)(b * S_LEN + m0) * S_LEN;
#pragma unroll
    for (int i = 0; i < 4; ++i)
#pragma unroll
        for (int j = 0; j < 4; ++j)
#pragma unroll
            for (int r = 0; r < 4; ++r) {
                int gm = wm + i * 16 + quad * 4 + r;
                int gn = n0 + wn + j * 16 + l16;
                prow[(size_t)gm * S_LEN + gn] = f2bf(__expf(acc[i][j][r] * scale));
            }
}

// -------- norm: per row, sum bf16 e; write normalized fp32 probs to d_out + inv_sum --------
__global__ __launch_bounds__(256) void k_norm(const u16* __restrict__ Pb,
                                              float* __restrict__ probs,
                                              float* __restrict__ inv_sums) {
    __shared__ float red[4];
    const int row = blockIdx.x;
    const u16* pr = Pb + (size_t)row * S_LEN;
    float* outr = probs + (size_t)row * S_LEN;
    const int tid = threadIdx.x, lane = tid & 63, w = tid >> 6;

    bf16x8 pv = *(const bf16x8*)(pr + (size_t)tid * 8);
    float f[8];
#pragma unroll
    for (int k = 0; k < 8; ++k) f[k] = bf2f((u16)pv[k]);

    float sum = ((f[0] + f[1]) + (f[2] + f[3])) + ((f[4] + f[5]) + (f[6] + f[7]));
#pragma unroll
    for (int off = 32; off > 0; off >>= 1) sum += __shfl_xor(sum, off);
    if (lane == 0) red[w] = sum;
    __syncthreads();
    sum = (red[0] + red[1]) + (red[2] + red[3]);
    float inv = 1.0f / sum;
    if (tid == 0) inv_sums[row] = inv;

    f32x4 o0, o1;
    o0.x = f[0] * inv; o0.y = f[1] * inv; o0.z = f[2] * inv; o0.w = f[3] * inv;
    o1.x = f[4] * inv; o1.y = f[5] * inv; o1.z = f[6] * inv; o1.w = f[7] * inv;
    *(f32x4*)(outr + (size_t)tid * 8) = o0;
    *(f32x4*)(outr + (size_t)tid * 8 + 4) = o1;
}

// -------- weighted = (e * V) * inv_sum; 128x64 tiles, BK=64 as two 32-planes --------
// 1D grid, nwg = 512 = (z=4) x (y=16) x (x=8); chunk = 64 per XCD
// -> the 8 n-blocks sharing each 512 KB Pb panel co-reside on one XCD.
__global__ __launch_bounds__(256) void k_pv(const u16* __restrict__ Pb, const u16* __restrict__ VT,
                                            const float* __restrict__ inv_sums,
                                            float* __restrict__ wout) {
    // A: 2 planes x (128x32) u16 @ 0 / 4096; B: 2 planes x (64x32) u16 @ 8192 / 10240
    __shared__ __align__(16) u16 lds[12288];
    u16* ldsA = lds;
    u16* ldsB = lds + 8192;
    const int l  = xcd_swz(blockIdx.x, 64);
    const int bx = l & 7;
    const int by = (l >> 3) & 15;
    const int b  = l >> 7;
    const int m0 = by * 128, n0 = bx * 64;
    const u16* A = Pb + (size_t)(b * S_LEN + m0) * S_LEN;
    const u16* B = VT + (size_t)b * DQ * S_LEN + (size_t)n0 * S_LEN;

    const int tid  = threadIdx.x;
    const int lane = tid & 63;
    const int w    = tid >> 6;
    const int wm   = (w & 1) << 6;      // 0 / 64
    const int wn   = (w >> 1) << 5;     // 0 / 32
    const int l16  = lane & 15;
    const int quad = lane >> 4;

    f32x4 acc[4][2];
#pragma unroll
    for (int i = 0; i < 4; ++i)
#pragma unroll
        for (int j = 0; j < 2; ++j) acc[i][j] = (f32x4)0.0f;

    for (int k0 = 0; k0 < S_LEN; k0 += 64) {
#pragma unroll
        for (int h = 0; h < 2; ++h) {
            // A plane h: 512 chunks of 16B
#pragma unroll
            for (int it = 0; it < 2; ++it) {
                int c  = it * 256 + tid;
                int r  = c >> 2;
                int cc = (c & 3) << 3;
                async16(A + (size_t)r * S_LEN + k0 + h * 32 + cc, ldsA + h * 4096 + r * 32 + cc);
            }
            // B plane h: 256 chunks
            {
                int r  = tid >> 2;
                int cc = (tid & 3) << 3;
                async16(B + (size_t)r * S_LEN + k0 + h * 32 + cc, ldsB + h * 2048 + r * 32 + cc);
            }
        }
        __syncthreads();
        bf16x8 af[2][4], bfr[2][2];
#pragma unroll
        for (int h = 0; h < 2; ++h) {
#pragma unroll
            for (int i = 0; i < 4; ++i)
                af[h][i] = *(const bf16x8*)(ldsA + h * 4096 + (wm + i * 16 + l16) * 32 + quad * 8);
#pragma unroll
            for (int j = 0; j < 2; ++j)
                bfr[h][j] = *(const bf16x8*)(ldsB + h * 2048 + (wn + j * 16 + l16) * 32 + quad * 8);
        }
#pragma unroll
        for (int h = 0; h < 2; ++h)
#pragma unroll
            for (int i = 0; i < 4; ++i)
#pragma unroll
                for (int j = 0; j < 2; ++j)
                    acc[i][j] = __builtin_amdgcn_mfma_f32_16x16x32_bf16(af[h][i], bfr[h][j], acc[i][j], 0, 0, 0);
        __syncthreads();
    }

    const float* invb = inv_sums + b * S_LEN;
    float* outb = wout + (size_t)b * S_LEN * DQ;
#pragma unroll
    for (int i = 0; i < 4; ++i) {
#pragma unroll
        for (int r = 0; r < 4; ++r) {
            int gm = m0 + wm + i * 16 + quad * 4 + r;
            float inv = invb[gm];   // inv_sums indexed by token within batch
#pragma unroll
            for (int j = 0; j < 2; ++j) {
                int gn = n0 + wn + j * 16 + l16;
                outb[(size_t)gm * DQ + gn] = acc[i][j][r] * inv;
            }
        }
    }
}

extern "C" void kernel_launch(void* const* d_in, const int* in_sizes, int n_in,
                              void* d_out, int out_size, void* d_ws, size_t ws_size,
                              hipStream_t stream) {
    const float* x  = (const float*)d_in[0];
    const float* Wq = (const float*)d_in[1];
    const float* bq = (const float*)d_in[2];
    const float* Wk = (const float*)d_in[3];
    const float* bk = (const float*)d_in[4];
    const float* Wv = (const float*)d_in[5];
    const float* bv = (const float*)d_in[6];

    char* ws = (char*)d_ws;
    u16* xb  = (u16*)(ws);                 // x bf16        [8192][512]   8.39 MB
    u16* Wb  = (u16*)(ws + 8388608);       // Wq,Wk,Wv bf16 3x[512][512]  1.57 MB
    u16* Qb  = (u16*)(ws + 9961472);       // Q bf16        [8192][512]
    u16* Kb  = (u16*)(ws + 18350080);      // K bf16        [8192][512]
    u16* VTb = (u16*)(ws + 35127296);      // V^T bf16      [4][512][2048]
    u16* Pb  = (u16*)(ws + 43515904);      // e bf16 (unnormalized) [8192][2048]  33.6 MB
    float* inv_sums = (float*)(ws + 77070336); // [8192] fp32
    float* probs = (float*)d_out;                        // [4][2048][2048]
    float* wout  = (float*)d_out + 16777216;             // [4][2048][512]

    k_cvt_all<<<4864, 256, 0, stream>>>(x, Wq, Wk, Wv, xb, Wb);
    k_proj<<<768, 256, 0, stream>>>(xb, Wb, bq, bk, bv, Qb, VTb);
    k_scores<<<1024, 256, 0, stream>>>(Qb, Kb, Pb);
    k_norm<<<8192, 256, 0, stream>>>(Pb, probs, inv_sums);
    k_pv<<<512, 256, 0, stream>>>(Pb, VTb, inv_sums, wout);
}